// Round 1
// 333.382 us; speedup vs baseline: 1.0589x; 1.0589x over previous
//
#include <hip/hip_runtime.h>
#include <math.h>

#define EPSV 1e-5f
#define B 8
#define C 1024
#define C2 512
#define RK 73
#define HW 784      // 28*28
#define QW 3136     // 56*56

typedef __attribute__((ext_vector_type(8))) short bf16x8;
typedef __attribute__((ext_vector_type(4))) float f32x4;

__device__ __forceinline__ unsigned short f2bf(float f) {
    unsigned u = __float_as_uint(f);
    return (unsigned short)((u + 0x7fffu + ((u >> 16) & 1u)) >> 16);
}
__device__ __forceinline__ float ld_f(const float* p) { return *p; }
__device__ __forceinline__ float ld_f(const unsigned short* p) {
    return __uint_as_float(((unsigned)*p) << 16);
}

// ---------- kernel 1: global average pool over y -> s0 ----------
__global__ void gap_kernel(const float* __restrict__ y, float* __restrict__ s0) {
    int bc = blockIdx.x;
    const float* p = y + (size_t)bc * QW;
    float sum = 0.f;
    for (int i = threadIdx.x; i < QW; i += 256) sum += p[i];
    for (int off = 32; off > 0; off >>= 1) sum += __shfl_down(sum, off, 64);
    __shared__ float red[4];
    if ((threadIdx.x & 63) == 0) red[threadIdx.x >> 6] = sum;
    __syncthreads();
    if (threadIdx.x == 0)
        s0[bc] = (red[0] + red[1] + red[2] + red[3]) * (1.0f / QW);
}

// ---------- kernel 2: SE FC layers ----------
__global__ void se_fc_kernel(const float* __restrict__ s0,
                             const float* __restrict__ fc1_w,
                             const float* __restrict__ fc2_w,
                             float* __restrict__ att) {
    int b = blockIdx.x;
    __shared__ float sv[C2];
    __shared__ float hv[RK];
    for (int i = threadIdx.x; i < C2; i += 256) sv[i] = s0[b * C2 + i];
    __syncthreads();
    if (threadIdx.x < RK) {
        float acc = 0.f;
        const float* wr = fc1_w + threadIdx.x * C2;
        for (int k = 0; k < C2; ++k) acc += wr[k] * sv[k];
        hv[threadIdx.x] = fmaxf(acc, 0.f);
    }
    __syncthreads();
    for (int o = threadIdx.x; o < C2; o += 256) {
        float acc = 0.f;
        const float* wr = fc2_w + o * RK;
        for (int j = 0; j < RK; ++j) acc += wr[j] * hv[j];
        att[b * C2 + o] = 1.f / (1.f + expf(-acc));
    }
}

// ---------- kernel 3: depthwise 3x3 conv + row-centered cov -> bf16 ----------
__global__ void dwcov_kernel(const float* __restrict__ x,
                             const float* __restrict__ dw_w,
                             const float* __restrict__ dw_b,
                             unsigned short* __restrict__ cov) {
    int bc = blockIdx.x;
    int c = bc & (C - 1);
    __shared__ float xs[HW];
    __shared__ float x1[HW];
    __shared__ float rm[28];
    const float* px = x + (size_t)bc * HW;
    for (int i = threadIdx.x; i < HW; i += 256) xs[i] = px[i];
    float wk[9];
#pragma unroll
    for (int j = 0; j < 9; ++j) wk[j] = dw_w[c * 9 + j];
    float bias = dw_b[c];
    __syncthreads();
    for (int p = threadIdx.x; p < HW; p += 256) {
        int h = p / 28, w = p - h * 28;
        float acc = bias;
#pragma unroll
        for (int dh = 0; dh < 3; ++dh) {
            int hh = h + dh - 1;
            if (hh < 0 || hh >= 28) continue;
#pragma unroll
            for (int dw = 0; dw < 3; ++dw) {
                int ww = w + dw - 1;
                if (ww < 0 || ww >= 28) continue;
                acc += xs[hh * 28 + ww] * wk[dh * 3 + dw];
            }
        }
        x1[p] = acc;
    }
    __syncthreads();
    if (threadIdx.x < 28) {
        float s = 0.f;
        for (int w = 0; w < 28; ++w) s += x1[threadIdx.x * 28 + w];
        rm[threadIdx.x] = s * (1.f / 28.f);
    }
    __syncthreads();
    unsigned short* pc = cov + (size_t)bc * HW;
    for (int p = threadIdx.x; p < HW; p += 256) {
        int h = p / 28, g = p - h * 28;
        float mh = rm[h], mg = rm[g];
        float acc = 0.f;
        for (int w = 0; w < 28; ++w)
            acc += (x1[h * 28 + w] - mh) * (x1[g * 28 + w] - mg);
        pc[p] = f2bf(acc * (1.f / 27.f));
    }
}

// ---------- pack weights bf16; fold att into per-batch w1y; fold bias+bn ----------
__global__ void pack_w(const float* __restrict__ conv_w, const float* __restrict__ conv_b,
                       const float* __restrict__ conv1_w, const float* __restrict__ conv1_b,
                       const float* __restrict__ bn_g, const float* __restrict__ bn_b,
                       const float* __restrict__ bn_m, const float* __restrict__ bn_v,
                       const float* __restrict__ att,
                       unsigned short* __restrict__ w0b, unsigned short* __restrict__ w1y,
                       unsigned short* __restrict__ w1pT,
                       float* __restrict__ sA, float* __restrict__ sB0, float* __restrict__ sB1) {
    int o = blockIdx.x, t = threadIdx.x;
    for (int i = t; i < C; i += 256) w0b[(size_t)o * C + i] = f2bf(conv_w[(size_t)o * C + i]);
    for (int i = t; i < 1536; i += 256) w1pT[(size_t)o * 1536 + i] = f2bf(conv1_w[(size_t)o * 2048 + 512 + i]);
#pragma unroll
    for (int b = 0; b < B; ++b)
        for (int c = t; c < C2; c += 256)
            w1y[((size_t)b * C2 + o) * C2 + c] = f2bf(conv1_w[(size_t)o * 2048 + c] * att[b * C2 + c]);
    if (t == 0) {
        float sc = rsqrtf(bn_v[o] + EPSV) * bn_g[o];
        float bi = bn_b[o] - bn_m[o] * sc;
        sA[o] = sc;
        sB0[o] = conv_b[o] * sc + bi;
        sB1[o] = conv1_b[o] * sc + bi;
    }
}

// ---------- tiled transpose+convert: src[b][rows][cols] -> dst[(b,col)][dpitch]+doff ----------
__global__ __launch_bounds__(256)
void transpose_pass(const float* __restrict__ src, unsigned short* __restrict__ dst,
                    int rows, int cols, int dpitch, int doff) {
    int b = blockIdx.z;
    int c0 = blockIdx.y * 64, p0 = blockIdx.x * 64;
    __shared__ float ts[64][65];
    int tid = threadIdx.x;
    int pl = tid & 63, r0 = tid >> 6;
    const float* sb = src + ((size_t)b * rows + c0) * cols + p0;
    if (p0 + pl < cols) {
#pragma unroll
        for (int j = 0; j < 16; ++j) {
            int cl = r0 + j * 4;
            ts[cl][pl] = sb[(size_t)cl * cols + pl];
        }
    }
    __syncthreads();
    int cl = tid & 63;
#pragma unroll
    for (int j = 0; j < 16; ++j) {
        int pl2 = r0 + j * 4;
        if (p0 + pl2 < cols)
            dst[((size_t)b * cols + p0 + pl2) * dpitch + doff + c0 + cl] = f2bf(ts[cl][pl2]);
    }
}

// ---------- MFMA GEMM: 64o x 64n, BK=32, VGPR double-buffered staging ----------
// XCD-aware bijective swizzle: XCD = linear_block_id % 8 (grid.x % 8 == 0 keeps this
// true under blockIdx.z). Decode r = bx&7 (XCD class), t = r*TPC + (bx>>3)>>3,
// og = (bx>>3)&7 -> all 8 o-blocks of one n-tile share an XCD, so the B-slice is
// fetched into exactly one L2 once (was: o-fastest -> 8 XCDs each streamed full B).
// Tiles padded to 8*TPC; blocks with t >= NT exit before any barrier.
// MODE 0: A=w0b, B=cov_bf bf16 strided (stride HW), N=6272(b,p); epi bn+sigmoid -> BcatT cols 0..511
// MODE 1: A=w1pT, B=BcatT contiguous rows (pitch 1536), N=6272; epi f2bf -> Pb [b][o][784]
// MODE 2: A=w1y[b], B=y f32 strided (stride QW), N=3136 (z=b); epi (acc+up(Pb))*bn relu -> out
template<int MODE, int K>
__global__ __launch_bounds__(256)
void mfma_gemm(const unsigned short* __restrict__ wpk,
               const void* __restrict__ bsrc_v,
               const unsigned short* __restrict__ Pb,
               const float* __restrict__ sA, const float* __restrict__ sB,
               void* __restrict__ outv) {
    constexpr int NIT = K / 32;
    constexpr int NT  = (MODE == 2) ? 49 : 98;   // real n-tiles
    constexpr int TPC = (NT + 7) / 8;            // tiles per XCD class (7 or 13)
    int bx = blockIdx.x;
    int r = bx & 7, i = bx >> 3;
    int t = r * TPC + (i >> 3);
    if (t >= NT) return;
    int o0 = (i & 7) * 64;
    int n0 = t * 64;
    int b = blockIdx.z;
    union SM {
        struct { __align__(16) unsigned short Wt[2][2560]; __align__(16) unsigned short At[2][2560]; } s;
        float pt[(MODE == 2) ? 64 * 84 : 4];
    };
    __shared__ SM sm;
    int tid = threadIdx.x;
    int lane = tid & 63, wv = tid >> 6;
    int ln = lane & 15, quad = lane >> 4;
    int o_w = (wv >> 1) * 32, q_w = (wv & 1) * 32;
    int swr = tid >> 2, swk = (tid & 3) * 8;   // 16B staging: row, k-off
    int s_gq = tid & 63, s_gk8 = tid >> 6;     // strided staging: n, k-octet
    int qg = n0 + s_gq;
    const unsigned short* wp = (MODE == 2) ? wpk + (size_t)b * C2 * C2 : wpk;
    const unsigned short* wg = wp + (size_t)(o0 + swr) * K + swk;
    // B pointers
    const unsigned short* bg_s = nullptr;  // MODE0 strided bf16
    const unsigned short* bg_c = nullptr;  // MODE1 contiguous
    const float* bg_f = nullptr;           // MODE2 strided f32
    if (MODE == 0) {
        int bq = qg / HW, pp = qg - bq * HW;
        bg_s = (const unsigned short*)bsrc_v + ((size_t)bq * C + s_gk8 * 8) * HW + pp;
    } else if (MODE == 1) {
        bg_c = (const unsigned short*)bsrc_v + (size_t)(n0 + swr) * K + swk;
    } else {
        bg_f = (const float*)bsrc_v + ((size_t)b * C2 + s_gk8 * 8) * QW + qg;
    }

    // prologue: chunk 0 -> LDS[0]
    {
        float4 wv4 = *(const float4*)wg;
        *(float4*)&sm.s.Wt[0][swr * 40 + swk] = wv4;
        unsigned short pk[8];
        if (MODE == 0) {
#pragma unroll
            for (int j = 0; j < 8; ++j) pk[j] = bg_s[(size_t)j * HW];
            *(float4*)&sm.s.At[0][s_gq * 40 + s_gk8 * 8] = *(float4*)pk;
        } else if (MODE == 1) {
            *(float4*)&sm.s.At[0][swr * 40 + swk] = *(const float4*)bg_c;
        } else {
#pragma unroll
            for (int j = 0; j < 8; ++j) pk[j] = f2bf(bg_f[(size_t)j * QW]);
            *(float4*)&sm.s.At[0][s_gq * 40 + s_gk8 * 8] = *(float4*)pk;
        }
    }
    __syncthreads();

    f32x4 acc[2][2] = {};
    for (int i2 = 0; i2 < NIT; ++i2) {
        int cur = i2 & 1;
        float4 wn;
        unsigned short bn[8];
        if (i2 + 1 < NIT) {               // prefetch next chunk into VGPRs
            wn = *(const float4*)(wg + (size_t)(i2 + 1) * 32);
            if (MODE == 0) {
                const unsigned short* s = bg_s + (size_t)(i2 + 1) * 32 * HW;
#pragma unroll
                for (int j = 0; j < 8; ++j) bn[j] = s[(size_t)j * HW];
            } else if (MODE == 1) {
                *(float4*)bn = *(const float4*)(bg_c + (size_t)(i2 + 1) * 32);
            } else {
                const float* s = bg_f + (size_t)(i2 + 1) * 32 * QW;
#pragma unroll
                for (int j = 0; j < 8; ++j) bn[j] = f2bf(s[(size_t)j * QW]);
            }
        }
        bf16x8 af[2], bfr[2];
#pragma unroll
        for (int mt = 0; mt < 2; ++mt)
            af[mt] = *(const bf16x8*)&sm.s.Wt[cur][(o_w + mt * 16 + ln) * 40 + quad * 8];
#pragma unroll
        for (int nt = 0; nt < 2; ++nt)
            bfr[nt] = *(const bf16x8*)&sm.s.At[cur][(q_w + nt * 16 + ln) * 40 + quad * 8];
#pragma unroll
        for (int mt = 0; mt < 2; ++mt)
#pragma unroll
            for (int nt = 0; nt < 2; ++nt)
                acc[mt][nt] = __builtin_amdgcn_mfma_f32_16x16x32_bf16(af[mt], bfr[nt], acc[mt][nt], 0, 0, 0);
        if (i2 + 1 < NIT) {
            int nxt = cur ^ 1;
            *(float4*)&sm.s.Wt[nxt][swr * 40 + swk] = wn;
            if (MODE == 1) *(float4*)&sm.s.At[nxt][swr * 40 + swk] = *(float4*)bn;
            else           *(float4*)&sm.s.At[nxt][s_gq * 40 + s_gk8 * 8] = *(float4*)bn;
            __syncthreads();
        }
    }

    // ---- epilogue; D: row = quad*4+reg, col = ln ----
    if (MODE == 2) {
        float* outp = (float*)outv;
        __syncthreads();
        int h0 = n0 / 56;
        int hmin = (h0 & 1) ? (h0 >> 1) : max(0, (h0 >> 1) - 1);
        for (int e = tid; e < 64 * 84; e += 256) {
            int o_l = e / 84, rem = e - o_l * 84;
            int s = rem / 28, w = rem - s * 28;
            int row = min(hmin + s, 27);
            sm.pt[e] = ld_f(&Pb[((size_t)b * C2 + o0 + o_l) * HW + row * 28 + w]);
        }
        __syncthreads();
#pragma unroll
        for (int nt = 0; nt < 2; ++nt) {
            int q = n0 + q_w + nt * 16 + ln;
            int hq = q / 56, wq = q - hq * 56;
            int hm = hq >> 1, wm = wq >> 1;
            int hn = (hq & 1) ? min(hm + 1, 27) : max(hm - 1, 0);
            int wn_ = (wq & 1) ? min(wm + 1, 27) : max(wm - 1, 0);
            int rm_ = (hm - hmin) * 28, rn_ = (hn - hmin) * 28;
#pragma unroll
            for (int mt = 0; mt < 2; ++mt)
#pragma unroll
                for (int reg = 0; reg < 4; ++reg) {
                    int ol = o_w + mt * 16 + quad * 4 + reg;
                    int o = o0 + ol;
                    const float* Pt = &sm.pt[ol * 84];
                    float up = 0.5625f * Pt[rm_ + wm] + 0.1875f * (Pt[rm_ + wn_] + Pt[rn_ + wm])
                             + 0.0625f * Pt[rn_ + wn_];
                    float v = (acc[mt][nt][reg] + up) * sA[o] + sB[o];
                    outp[((size_t)b * C2 + o) * QW + q] = fmaxf(v, 0.f);
                }
        }
    } else if (MODE == 0) {
        unsigned short* outp = (unsigned short*)outv;   // BcatT, pitch 1536, cols 0..511
#pragma unroll
        for (int nt = 0; nt < 2; ++nt) {
            int n = n0 + q_w + nt * 16 + ln;
#pragma unroll
            for (int mt = 0; mt < 2; ++mt) {
                int ob = o0 + o_w + mt * 16 + quad * 4;
                unsigned short pk[4];
#pragma unroll
                for (int reg = 0; reg < 4; ++reg) {
                    int o = ob + reg;
                    float v = acc[mt][nt][reg] * sA[o] + sB[o];
                    pk[reg] = f2bf(1.f / (1.f + expf(-v)));
                }
                *(uint2*)&outp[(size_t)n * 1536 + ob] = *(uint2*)pk;
            }
        }
    } else {
        unsigned short* outp = (unsigned short*)outv;   // Pb [b][o][784] bf16
#pragma unroll
        for (int nt = 0; nt < 2; ++nt) {
            int n = n0 + q_w + nt * 16 + ln;
            int be = n / HW, pe = n - be * HW;
#pragma unroll
            for (int mt = 0; mt < 2; ++mt)
#pragma unroll
                for (int reg = 0; reg < 4; ++reg) {
                    int o = o0 + o_w + mt * 16 + quad * 4 + reg;
                    outp[((size_t)be * C2 + o) * HW + pe] = f2bf(acc[mt][nt][reg]);
                }
        }
    }
}

extern "C" void kernel_launch(void* const* d_in, const int* in_sizes, int n_in,
                              void* d_out, int out_size, void* d_ws, size_t ws_size,
                              hipStream_t stream) {
    const float* y       = (const float*)d_in[0];
    const float* x       = (const float*)d_in[1];
    const float* fc1_w   = (const float*)d_in[2];
    const float* fc2_w   = (const float*)d_in[3];
    const float* conv_w  = (const float*)d_in[4];
    const float* conv_b  = (const float*)d_in[5];
    const float* conv1_w = (const float*)d_in[6];
    const float* conv1_b = (const float*)d_in[7];
    const float* bn_g    = (const float*)d_in[8];
    const float* bn_b    = (const float*)d_in[9];
    const float* bn_m    = (const float*)d_in[10];
    const float* bn_v    = (const float*)d_in[11];
    const float* dw_w    = (const float*)d_in[12];
    const float* dw_b    = (const float*)d_in[13];
    float* out = (float*)d_out;

    // ---- workspace carve: NO aliasing; total = 45,389,824 B (== Round-2-proven extent) ----
    float* ws  = (float*)d_ws;
    float* s0  = ws;                 // 4096
    float* att = ws + 4096;          // 4096
    float* sA  = ws + 8192;          // 512
    float* sB0 = ws + 8704;          // 512
    float* sB1 = ws + 9216;          // 512 -> header ends at float 9728 (byte 38912, 16B-aligned)
    unsigned short* w0b    = (unsigned short*)(ws + 9728);   // 512*1024 sh
    unsigned short* w1y    = w0b + (size_t)C2 * C;           // 8*512*512 sh
    unsigned short* w1pT   = w1y + (size_t)B * C2 * C2;      // 512*1536 sh
    unsigned short* cov_bf = w1pT + (size_t)C2 * 1536;       // 8*1024*784 sh
    unsigned short* BcatT  = cov_bf + (size_t)B * C * HW;    // 6272*1536 sh
    unsigned short* Pb     = BcatT + (size_t)B * HW * 1536;  // 8*512*784 sh

    gap_kernel<<<B * C2, 256, 0, stream>>>(y, s0);
    se_fc_kernel<<<B, 256, 0, stream>>>(s0, fc1_w, fc2_w, att);
    pack_w<<<C2, 256, 0, stream>>>(conv_w, conv_b, conv1_w, conv1_b,
                                   bn_g, bn_b, bn_m, bn_v, att,
                                   w0b, w1y, w1pT, sA, sB0, sB1);
    dwcov_kernel<<<B * C, 256, 0, stream>>>(x, dw_w, dw_b, cov_bf);
    // xT: x[b][c][p] -> BcatT[(b,p)][512+c]
    transpose_pass<<<dim3(13, 16, B), 256, 0, stream>>>(x, BcatT, C, HW, 1536, 512);
    // M0: x2s = sigmoid(bn(conv(cov))) -> BcatT cols 0..511  (98 tiles -> 13/class, grid 13*8*8)
    mfma_gemm<0, 1024><<<dim3(832), 256, 0, stream>>>(w0b, cov_bf, nullptr, sA, sB0, BcatT);
    // M1: Pb = w1[:,512:]·[x2s|x]  (bf16)
    mfma_gemm<1, 1536><<<dim3(832), 256, 0, stream>>>(w1pT, BcatT, nullptr, sA, sB0, Pb);
    // M2: out = relu(bn(w1y[b]·y + up(Pb)))  (49 tiles -> 7/class, grid 7*8*8 per batch)
    mfma_gemm<2, 512><<<dim3(448, 1, B), 256, 0, stream>>>(w1y, y, Pb, sA, sB1, out);
}

// Round 2
// 332.640 us; speedup vs baseline: 1.0613x; 1.0022x over previous
//
#include <hip/hip_runtime.h>
#include <math.h>

#define EPSV 1e-5f
#define B 8
#define C 1024
#define C2 512
#define RK 73
#define HW 784      // 28*28
#define QW 3136     // 56*56

typedef __attribute__((ext_vector_type(8))) short bf16x8;
typedef __attribute__((ext_vector_type(4))) float f32x4;

__device__ __forceinline__ unsigned short f2bf(float f) {
    unsigned u = __float_as_uint(f);
    return (unsigned short)((u + 0x7fffu + ((u >> 16) & 1u)) >> 16);
}
__device__ __forceinline__ unsigned cvt_pk_bf16(float lo, float hi) {
    unsigned r;
    asm("v_cvt_pk_bf16_f32 %0, %1, %2" : "=v"(r) : "v"(lo), "v"(hi));
    return r;
}
__device__ __forceinline__ float ld_f(const float* p) { return *p; }
__device__ __forceinline__ float ld_f(const unsigned short* p) {
    return __uint_as_float(((unsigned)*p) << 16);
}

// ---------- kernel 1: global average pool over y -> s0 ----------
__global__ void gap_kernel(const float* __restrict__ y, float* __restrict__ s0) {
    int bc = blockIdx.x;
    const float* p = y + (size_t)bc * QW;
    float sum = 0.f;
    for (int i = threadIdx.x; i < QW; i += 256) sum += p[i];
    for (int off = 32; off > 0; off >>= 1) sum += __shfl_down(sum, off, 64);
    __shared__ float red[4];
    if ((threadIdx.x & 63) == 0) red[threadIdx.x >> 6] = sum;
    __syncthreads();
    if (threadIdx.x == 0)
        s0[bc] = (red[0] + red[1] + red[2] + red[3]) * (1.0f / QW);
}

// ---------- kernel 2: SE FC layers ----------
__global__ void se_fc_kernel(const float* __restrict__ s0,
                             const float* __restrict__ fc1_w,
                             const float* __restrict__ fc2_w,
                             float* __restrict__ att) {
    int b = blockIdx.x;
    __shared__ float sv[C2];
    __shared__ float hv[RK];
    for (int i = threadIdx.x; i < C2; i += 256) sv[i] = s0[b * C2 + i];
    __syncthreads();
    if (threadIdx.x < RK) {
        float acc = 0.f;
        const float* wr = fc1_w + threadIdx.x * C2;
        for (int k = 0; k < C2; ++k) acc += wr[k] * sv[k];
        hv[threadIdx.x] = fmaxf(acc, 0.f);
    }
    __syncthreads();
    for (int o = threadIdx.x; o < C2; o += 256) {
        float acc = 0.f;
        const float* wr = fc2_w + o * RK;
        for (int j = 0; j < RK; ++j) acc += wr[j] * hv[j];
        att[b * C2 + o] = 1.f / (1.f + expf(-acc));
    }
}

// ---------- kernel 3: depthwise 3x3 conv + row-centered cov -> bf16 ----------
__global__ void dwcov_kernel(const float* __restrict__ x,
                             const float* __restrict__ dw_w,
                             const float* __restrict__ dw_b,
                             unsigned short* __restrict__ cov) {
    int bc = blockIdx.x;
    int c = bc & (C - 1);
    __shared__ float xs[HW];
    __shared__ float x1[HW];
    __shared__ float rm[28];
    const float* px = x + (size_t)bc * HW;
    for (int i = threadIdx.x; i < HW; i += 256) xs[i] = px[i];
    float wk[9];
#pragma unroll
    for (int j = 0; j < 9; ++j) wk[j] = dw_w[c * 9 + j];
    float bias = dw_b[c];
    __syncthreads();
    for (int p = threadIdx.x; p < HW; p += 256) {
        int h = p / 28, w = p - h * 28;
        float acc = bias;
#pragma unroll
        for (int dh = 0; dh < 3; ++dh) {
            int hh = h + dh - 1;
            if (hh < 0 || hh >= 28) continue;
#pragma unroll
            for (int dw = 0; dw < 3; ++dw) {
                int ww = w + dw - 1;
                if (ww < 0 || ww >= 28) continue;
                acc += xs[hh * 28 + ww] * wk[dh * 3 + dw];
            }
        }
        x1[p] = acc;
    }
    __syncthreads();
    if (threadIdx.x < 28) {
        float s = 0.f;
        for (int w = 0; w < 28; ++w) s += x1[threadIdx.x * 28 + w];
        rm[threadIdx.x] = s * (1.f / 28.f);
    }
    __syncthreads();
    unsigned short* pc = cov + (size_t)bc * HW;
    for (int p = threadIdx.x; p < HW; p += 256) {
        int h = p / 28, g = p - h * 28;
        float mh = rm[h], mg = rm[g];
        float acc = 0.f;
        for (int w = 0; w < 28; ++w)
            acc += (x1[h * 28 + w] - mh) * (x1[g * 28 + w] - mg);
        pc[p] = f2bf(acc * (1.f / 27.f));
    }
}

// ---------- pack weights bf16; fold att into per-batch w1y; fold bias+bn ----------
__global__ void pack_w(const float* __restrict__ conv_w, const float* __restrict__ conv_b,
                       const float* __restrict__ conv1_w, const float* __restrict__ conv1_b,
                       const float* __restrict__ bn_g, const float* __restrict__ bn_b,
                       const float* __restrict__ bn_m, const float* __restrict__ bn_v,
                       const float* __restrict__ att,
                       unsigned short* __restrict__ w0b, unsigned short* __restrict__ w1y,
                       unsigned short* __restrict__ w1pT,
                       float* __restrict__ sA, float* __restrict__ sB0, float* __restrict__ sB1) {
    int o = blockIdx.x, t = threadIdx.x;
    for (int i = t; i < C; i += 256) w0b[(size_t)o * C + i] = f2bf(conv_w[(size_t)o * C + i]);
    for (int i = t; i < 1536; i += 256) w1pT[(size_t)o * 1536 + i] = f2bf(conv1_w[(size_t)o * 2048 + 512 + i]);
#pragma unroll
    for (int b = 0; b < B; ++b)
        for (int c = t; c < C2; c += 256)
            w1y[((size_t)b * C2 + o) * C2 + c] = f2bf(conv1_w[(size_t)o * 2048 + c] * att[b * C2 + c]);
    if (t == 0) {
        float sc = rsqrtf(bn_v[o] + EPSV) * bn_g[o];
        float bi = bn_b[o] - bn_m[o] * sc;
        sA[o] = sc;
        sB0[o] = conv_b[o] * sc + bi;
        sB1[o] = conv1_b[o] * sc + bi;
    }
}

// ---------- tiled transpose+convert: src[b][rows][cols] -> dst[(b,col)][dpitch]+doff ----------
__global__ __launch_bounds__(256)
void transpose_pass(const float* __restrict__ src, unsigned short* __restrict__ dst,
                    int rows, int cols, int dpitch, int doff) {
    int b = blockIdx.z;
    int c0 = blockIdx.y * 64, p0 = blockIdx.x * 64;
    __shared__ float ts[64][65];
    int tid = threadIdx.x;
    int pl = tid & 63, r0 = tid >> 6;
    const float* sb = src + ((size_t)b * rows + c0) * cols + p0;
    if (p0 + pl < cols) {
#pragma unroll
        for (int j = 0; j < 16; ++j) {
            int cl = r0 + j * 4;
            ts[cl][pl] = sb[(size_t)cl * cols + pl];
        }
    }
    __syncthreads();
    int cl = tid & 63;
#pragma unroll
    for (int j = 0; j < 16; ++j) {
        int pl2 = r0 + j * 4;
        if (p0 + pl2 < cols)
            dst[((size_t)b * cols + p0 + pl2) * dpitch + doff + c0 + cl] = f2bf(ts[cl][pl2]);
    }
}

// ---------- MFMA GEMM: 128o x 64n block tile, BK=32, VGPR double-buffered staging ----------
// 4 waves, each owns a 64o x 32n sub-tile -> 8 MFMA per wave per K-step (2x the old
// 64x64 tile), halving staging VALU per MFMA.
// XCD-aware bijective swizzle: XCD = bx % 8 (grid.x % 8 == 0 keeps this true under
// blockIdx.z). Decode r = bx&7 (XCD class), og = (bx>>3)&3, t = r*TPC + (bx>>3)>>2:
// all 4 o-blocks of one n-tile share an XCD -> B-slice fetched into one L2 once.
// Tiles padded to 8*TPC; blocks with t >= NT exit before any barrier.
// MODE 0: A=w0b, B=cov_bf bf16 strided (stride HW), N=6272(b,p); epi bn+sigmoid -> BcatT cols 0..511
// MODE 1: A=w1pT, B=BcatT contiguous rows (pitch 1536), N=6272; epi f2bf -> Pb [b][o][784]
// MODE 2: A=w1y[b], B=y f32 strided (stride QW), N=3136 (z=b); epi (acc+up(Pb))*bn relu -> out
template<int MODE, int K>
__global__ __launch_bounds__(256)
void mfma_gemm(const unsigned short* __restrict__ wpk,
               const void* __restrict__ bsrc_v,
               const unsigned short* __restrict__ Pb,
               const float* __restrict__ sA, const float* __restrict__ sB,
               void* __restrict__ outv) {
    constexpr int NIT = K / 32;
    constexpr int NT  = (MODE == 2) ? 49 : 98;   // real n-tiles
    constexpr int TPC = (NT + 7) / 8;            // tiles per XCD class (7 or 13)
    int bx = blockIdx.x;
    int r = bx & 7, ii = bx >> 3;
    int t = r * TPC + (ii >> 2);
    if (t >= NT) return;
    int o0 = (ii & 3) * 128;
    int n0 = t * 64;
    int b = blockIdx.z;
    union SM {
        struct { __align__(16) unsigned short Wt[2][5120]; __align__(16) unsigned short At[2][2560]; } s;
        float pt[(MODE == 2) ? 128 * 84 : 4];
    };
    __shared__ SM sm;
    int tid = threadIdx.x;
    int lane = tid & 63, wv = tid >> 6;
    int ln = lane & 15, quad = lane >> 4;
    int o_w = (wv >> 1) * 64, q_w = (wv & 1) * 32;
    int swr = tid >> 2, swk = (tid & 3) * 8;   // 16B staging: row, k-off
    int s_gq = tid & 63, s_gk8 = tid >> 6;     // strided staging: n, k-octet
    int qg = n0 + s_gq;
    const unsigned short* wp = (MODE == 2) ? wpk + (size_t)b * C2 * C2 : wpk;
    const unsigned short* wg = wp + (size_t)(o0 + swr) * K + swk;       // rows 0..63
    const unsigned short* wg2 = wg + (size_t)64 * K;                    // rows 64..127
    // B pointers
    const unsigned short* bg_s = nullptr;  // MODE0 strided bf16
    const unsigned short* bg_c = nullptr;  // MODE1 contiguous
    const float* bg_f = nullptr;           // MODE2 strided f32
    if (MODE == 0) {
        int bq = qg / HW, pp = qg - bq * HW;
        bg_s = (const unsigned short*)bsrc_v + ((size_t)bq * C + s_gk8 * 8) * HW + pp;
    } else if (MODE == 1) {
        bg_c = (const unsigned short*)bsrc_v + (size_t)(n0 + swr) * K + swk;
    } else {
        bg_f = (const float*)bsrc_v + ((size_t)b * C2 + s_gk8 * 8) * QW + qg;
    }

    // prologue: chunk 0 -> LDS[0]
    {
        float4 wv4 = *(const float4*)wg;
        float4 wv5 = *(const float4*)wg2;
        *(float4*)&sm.s.Wt[0][swr * 40 + swk] = wv4;
        *(float4*)&sm.s.Wt[0][(64 + swr) * 40 + swk] = wv5;
        if (MODE == 0) {
            unsigned short pk[8];
#pragma unroll
            for (int j = 0; j < 8; ++j) pk[j] = bg_s[(size_t)j * HW];
            *(float4*)&sm.s.At[0][s_gq * 40 + s_gk8 * 8] = *(float4*)pk;
        } else if (MODE == 1) {
            *(float4*)&sm.s.At[0][swr * 40 + swk] = *(const float4*)bg_c;
        } else {
            unsigned pk2[4];
#pragma unroll
            for (int j = 0; j < 4; ++j)
                pk2[j] = cvt_pk_bf16(bg_f[(size_t)(2 * j) * QW], bg_f[(size_t)(2 * j + 1) * QW]);
            *(float4*)&sm.s.At[0][s_gq * 40 + s_gk8 * 8] = *(float4*)pk2;
        }
    }
    __syncthreads();

    f32x4 acc[4][2] = {};
    for (int i2 = 0; i2 < NIT; ++i2) {
        int cur = i2 & 1;
        float4 wnA, wnB;
        unsigned short bn[8];
        unsigned bn2[4];
        if (i2 + 1 < NIT) {               // prefetch next chunk into VGPRs
            wnA = *(const float4*)(wg + (size_t)(i2 + 1) * 32);
            wnB = *(const float4*)(wg2 + (size_t)(i2 + 1) * 32);
            if (MODE == 0) {
                const unsigned short* s = bg_s + (size_t)(i2 + 1) * 32 * HW;
#pragma unroll
                for (int j = 0; j < 8; ++j) bn[j] = s[(size_t)j * HW];
            } else if (MODE == 1) {
                *(float4*)bn = *(const float4*)(bg_c + (size_t)(i2 + 1) * 32);
            } else {
                const float* s = bg_f + (size_t)(i2 + 1) * 32 * QW;
#pragma unroll
                for (int j = 0; j < 4; ++j)
                    bn2[j] = cvt_pk_bf16(s[(size_t)(2 * j) * QW], s[(size_t)(2 * j + 1) * QW]);
            }
        }
        bf16x8 af[4], bfr[2];
#pragma unroll
        for (int mt = 0; mt < 4; ++mt)
            af[mt] = *(const bf16x8*)&sm.s.Wt[cur][(o_w + mt * 16 + ln) * 40 + quad * 8];
#pragma unroll
        for (int nt = 0; nt < 2; ++nt)
            bfr[nt] = *(const bf16x8*)&sm.s.At[cur][(q_w + nt * 16 + ln) * 40 + quad * 8];
#pragma unroll
        for (int mt = 0; mt < 4; ++mt)
#pragma unroll
            for (int nt = 0; nt < 2; ++nt)
                acc[mt][nt] = __builtin_amdgcn_mfma_f32_16x16x32_bf16(af[mt], bfr[nt], acc[mt][nt], 0, 0, 0);
        if (i2 + 1 < NIT) {
            int nxt = cur ^ 1;
            *(float4*)&sm.s.Wt[nxt][swr * 40 + swk] = wnA;
            *(float4*)&sm.s.Wt[nxt][(64 + swr) * 40 + swk] = wnB;
            if (MODE == 1)      *(float4*)&sm.s.At[nxt][swr * 40 + swk] = *(float4*)bn;
            else if (MODE == 0) *(float4*)&sm.s.At[nxt][s_gq * 40 + s_gk8 * 8] = *(float4*)bn;
            else                *(float4*)&sm.s.At[nxt][s_gq * 40 + s_gk8 * 8] = *(float4*)bn2;
            __syncthreads();
        }
    }

    // ---- epilogue; D: row = quad*4+reg, col = ln ----
    if (MODE == 2) {
        float* outp = (float*)outv;
        __syncthreads();
        int h0 = n0 / 56;
        int hmin = (h0 & 1) ? (h0 >> 1) : max(0, (h0 >> 1) - 1);
        for (int e = tid; e < 128 * 84; e += 256) {
            int o_l = e / 84, rem = e - o_l * 84;
            int s = rem / 28, w = rem - s * 28;
            int row = min(hmin + s, 27);
            sm.pt[e] = ld_f(&Pb[((size_t)b * C2 + o0 + o_l) * HW + row * 28 + w]);
        }
        __syncthreads();
#pragma unroll
        for (int nt = 0; nt < 2; ++nt) {
            int q = n0 + q_w + nt * 16 + ln;
            int hq = q / 56, wq = q - hq * 56;
            int hm = hq >> 1, wm = wq >> 1;
            int hn = (hq & 1) ? min(hm + 1, 27) : max(hm - 1, 0);
            int wn_ = (wq & 1) ? min(wm + 1, 27) : max(wm - 1, 0);
            int rm_ = (hm - hmin) * 28, rn_ = (hn - hmin) * 28;
#pragma unroll
            for (int mt = 0; mt < 4; ++mt)
#pragma unroll
                for (int reg = 0; reg < 4; ++reg) {
                    int ol = o_w + mt * 16 + quad * 4 + reg;
                    int o = o0 + ol;
                    const float* Pt = &sm.pt[ol * 84];
                    float up = 0.5625f * Pt[rm_ + wm] + 0.1875f * (Pt[rm_ + wn_] + Pt[rn_ + wm])
                             + 0.0625f * Pt[rn_ + wn_];
                    float v = (acc[mt][nt][reg] + up) * sA[o] + sB[o];
                    outp[((size_t)b * C2 + o) * QW + q] = fmaxf(v, 0.f);
                }
        }
    } else if (MODE == 0) {
        unsigned short* outp = (unsigned short*)outv;   // BcatT, pitch 1536, cols 0..511
#pragma unroll
        for (int nt = 0; nt < 2; ++nt) {
            int n = n0 + q_w + nt * 16 + ln;
#pragma unroll
            for (int mt = 0; mt < 4; ++mt) {
                int ob = o0 + o_w + mt * 16 + quad * 4;
                unsigned short pk[4];
#pragma unroll
                for (int reg = 0; reg < 4; ++reg) {
                    int o = ob + reg;
                    float v = acc[mt][nt][reg] * sA[o] + sB[o];
                    pk[reg] = f2bf(1.f / (1.f + expf(-v)));
                }
                *(uint2*)&outp[(size_t)n * 1536 + ob] = *(uint2*)pk;
            }
        }
    } else {
        unsigned short* outp = (unsigned short*)outv;   // Pb [b][o][784] bf16
#pragma unroll
        for (int nt = 0; nt < 2; ++nt) {
            int n = n0 + q_w + nt * 16 + ln;
            int be = n / HW, pe = n - be * HW;
#pragma unroll
            for (int mt = 0; mt < 4; ++mt)
#pragma unroll
                for (int reg = 0; reg < 4; ++reg) {
                    int o = o0 + o_w + mt * 16 + quad * 4 + reg;
                    outp[((size_t)be * C2 + o) * HW + pe] = f2bf(acc[mt][nt][reg]);
                }
        }
    }
}

extern "C" void kernel_launch(void* const* d_in, const int* in_sizes, int n_in,
                              void* d_out, int out_size, void* d_ws, size_t ws_size,
                              hipStream_t stream) {
    const float* y       = (const float*)d_in[0];
    const float* x       = (const float*)d_in[1];
    const float* fc1_w   = (const float*)d_in[2];
    const float* fc2_w   = (const float*)d_in[3];
    const float* conv_w  = (const float*)d_in[4];
    const float* conv_b  = (const float*)d_in[5];
    const float* conv1_w = (const float*)d_in[6];
    const float* conv1_b = (const float*)d_in[7];
    const float* bn_g    = (const float*)d_in[8];
    const float* bn_b    = (const float*)d_in[9];
    const float* bn_m    = (const float*)d_in[10];
    const float* bn_v    = (const float*)d_in[11];
    const float* dw_w    = (const float*)d_in[12];
    const float* dw_b    = (const float*)d_in[13];
    float* out = (float*)d_out;

    // ---- workspace carve: NO aliasing; total = 45,389,824 B (== Round-2-proven extent) ----
    float* ws  = (float*)d_ws;
    float* s0  = ws;                 // 4096
    float* att = ws + 4096;          // 4096
    float* sA  = ws + 8192;          // 512
    float* sB0 = ws + 8704;          // 512
    float* sB1 = ws + 9216;          // 512 -> header ends at float 9728 (byte 38912, 16B-aligned)
    unsigned short* w0b    = (unsigned short*)(ws + 9728);   // 512*1024 sh
    unsigned short* w1y    = w0b + (size_t)C2 * C;           // 8*512*512 sh
    unsigned short* w1pT   = w1y + (size_t)B * C2 * C2;      // 512*1536 sh
    unsigned short* cov_bf = w1pT + (size_t)C2 * 1536;       // 8*1024*784 sh
    unsigned short* BcatT  = cov_bf + (size_t)B * C * HW;    // 6272*1536 sh
    unsigned short* Pb     = BcatT + (size_t)B * HW * 1536;  // 8*512*784 sh

    gap_kernel<<<B * C2, 256, 0, stream>>>(y, s0);
    se_fc_kernel<<<B, 256, 0, stream>>>(s0, fc1_w, fc2_w, att);
    pack_w<<<C2, 256, 0, stream>>>(conv_w, conv_b, conv1_w, conv1_b,
                                   bn_g, bn_b, bn_m, bn_v, att,
                                   w0b, w1y, w1pT, sA, sB0, sB1);
    dwcov_kernel<<<B * C, 256, 0, stream>>>(x, dw_w, dw_b, cov_bf);
    // xT: x[b][c][p] -> BcatT[(b,p)][512+c]
    transpose_pass<<<dim3(13, 16, B), 256, 0, stream>>>(x, BcatT, C, HW, 1536, 512);
    // M0: x2s = sigmoid(bn(conv(cov))) -> BcatT cols 0..511  (98 tiles, 4 o-blocks -> grid 8*4*13)
    mfma_gemm<0, 1024><<<dim3(416), 256, 0, stream>>>(w0b, cov_bf, nullptr, sA, sB0, BcatT);
    // M1: Pb = w1[:,512:]·[x2s|x]  (bf16)
    mfma_gemm<1, 1536><<<dim3(416), 256, 0, stream>>>(w1pT, BcatT, nullptr, sA, sB0, Pb);
    // M2: out = relu(bn(w1y[b]·y + up(Pb)))  (49 tiles, 4 o-blocks -> grid 8*4*7 per batch)
    mfma_gemm<2, 512><<<dim3(224, 1, B), 256, 0, stream>>>(w1y, y, Pb, sA, sB1, out);
}

// Round 3
// 320.328 us; speedup vs baseline: 1.1021x; 1.0384x over previous
//
#include <hip/hip_runtime.h>
#include <math.h>

#define EPSV 1e-5f
#define B 8
#define C 1024
#define C2 512
#define RK 73
#define HW 784      // 28*28
#define QW 3136     // 56*56

typedef __attribute__((ext_vector_type(8))) short bf16x8;
typedef __attribute__((ext_vector_type(4))) float f32x4;

__device__ __forceinline__ unsigned short f2bf(float f) {
    unsigned u = __float_as_uint(f);
    return (unsigned short)((u + 0x7fffu + ((u >> 16) & 1u)) >> 16);
}
__device__ __forceinline__ unsigned cvt_pk_bf16(float lo, float hi) {
    unsigned r;
    asm("v_cvt_pk_bf16_f32 %0, %1, %2" : "=v"(r) : "v"(lo), "v"(hi));
    return r;
}
__device__ __forceinline__ float ld_f(const float* p) { return *p; }
__device__ __forceinline__ float ld_f(const unsigned short* p) {
    return __uint_as_float(((unsigned)*p) << 16);
}

// ---------- kernel 1: global average pool over y -> s0 ----------
__global__ void gap_kernel(const float* __restrict__ y, float* __restrict__ s0) {
    int bc = blockIdx.x;
    const float* p = y + (size_t)bc * QW;
    float sum = 0.f;
    for (int i = threadIdx.x; i < QW; i += 256) sum += p[i];
    for (int off = 32; off > 0; off >>= 1) sum += __shfl_down(sum, off, 64);
    __shared__ float red[4];
    if ((threadIdx.x & 63) == 0) red[threadIdx.x >> 6] = sum;
    __syncthreads();
    if (threadIdx.x == 0)
        s0[bc] = (red[0] + red[1] + red[2] + red[3]) * (1.0f / QW);
}

// ---------- kernel 2: SE FC layers ----------
__global__ void se_fc_kernel(const float* __restrict__ s0,
                             const float* __restrict__ fc1_w,
                             const float* __restrict__ fc2_w,
                             float* __restrict__ att) {
    int b = blockIdx.x;
    __shared__ float sv[C2];
    __shared__ float hv[RK];
    for (int i = threadIdx.x; i < C2; i += 256) sv[i] = s0[b * C2 + i];
    __syncthreads();
    if (threadIdx.x < RK) {
        float acc = 0.f;
        const float* wr = fc1_w + threadIdx.x * C2;
        for (int k = 0; k < C2; ++k) acc += wr[k] * sv[k];
        hv[threadIdx.x] = fmaxf(acc, 0.f);
    }
    __syncthreads();
    for (int o = threadIdx.x; o < C2; o += 256) {
        float acc = 0.f;
        const float* wr = fc2_w + o * RK;
        for (int j = 0; j < RK; ++j) acc += wr[j] * hv[j];
        att[b * C2 + o] = 1.f / (1.f + expf(-acc));
    }
}

// ---------- kernel 3: depthwise 3x3 conv + row-centered cov -> bf16 ----------
__global__ void dwcov_kernel(const float* __restrict__ x,
                             const float* __restrict__ dw_w,
                             const float* __restrict__ dw_b,
                             unsigned short* __restrict__ cov) {
    int bc = blockIdx.x;
    int c = bc & (C - 1);
    __shared__ float xs[HW];
    __shared__ float x1[HW];
    __shared__ float rm[28];
    const float* px = x + (size_t)bc * HW;
    for (int i = threadIdx.x; i < HW; i += 256) xs[i] = px[i];
    float wk[9];
#pragma unroll
    for (int j = 0; j < 9; ++j) wk[j] = dw_w[c * 9 + j];
    float bias = dw_b[c];
    __syncthreads();
    for (int p = threadIdx.x; p < HW; p += 256) {
        int h = p / 28, w = p - h * 28;
        float acc = bias;
#pragma unroll
        for (int dh = 0; dh < 3; ++dh) {
            int hh = h + dh - 1;
            if (hh < 0 || hh >= 28) continue;
#pragma unroll
            for (int dw = 0; dw < 3; ++dw) {
                int ww = w + dw - 1;
                if (ww < 0 || ww >= 28) continue;
                acc += xs[hh * 28 + ww] * wk[dh * 3 + dw];
            }
        }
        x1[p] = acc;
    }
    __syncthreads();
    if (threadIdx.x < 28) {
        float s = 0.f;
        for (int w = 0; w < 28; ++w) s += x1[threadIdx.x * 28 + w];
        rm[threadIdx.x] = s * (1.f / 28.f);
    }
    __syncthreads();
    unsigned short* pc = cov + (size_t)bc * HW;
    for (int p = threadIdx.x; p < HW; p += 256) {
        int h = p / 28, g = p - h * 28;
        float mh = rm[h], mg = rm[g];
        float acc = 0.f;
        for (int w = 0; w < 28; ++w)
            acc += (x1[h * 28 + w] - mh) * (x1[g * 28 + w] - mg);
        pc[p] = f2bf(acc * (1.f / 27.f));
    }
}

// ---------- pack weights bf16; fold att into per-batch w1y; fold bias+bn ----------
__global__ void pack_w(const float* __restrict__ conv_w, const float* __restrict__ conv_b,
                       const float* __restrict__ conv1_w, const float* __restrict__ conv1_b,
                       const float* __restrict__ bn_g, const float* __restrict__ bn_b,
                       const float* __restrict__ bn_m, const float* __restrict__ bn_v,
                       const float* __restrict__ att,
                       unsigned short* __restrict__ w0b, unsigned short* __restrict__ w1y,
                       unsigned short* __restrict__ w1pT,
                       float* __restrict__ sA, float* __restrict__ sB0, float* __restrict__ sB1) {
    int o = blockIdx.x, t = threadIdx.x;
    for (int i = t; i < C; i += 256) w0b[(size_t)o * C + i] = f2bf(conv_w[(size_t)o * C + i]);
    for (int i = t; i < 1536; i += 256) w1pT[(size_t)o * 1536 + i] = f2bf(conv1_w[(size_t)o * 2048 + 512 + i]);
#pragma unroll
    for (int b = 0; b < B; ++b)
        for (int c = t; c < C2; c += 256)
            w1y[((size_t)b * C2 + o) * C2 + c] = f2bf(conv1_w[(size_t)o * 2048 + c] * att[b * C2 + c]);
    if (t == 0) {
        float sc = rsqrtf(bn_v[o] + EPSV) * bn_g[o];
        float bi = bn_b[o] - bn_m[o] * sc;
        sA[o] = sc;
        sB0[o] = conv_b[o] * sc + bi;
        sB1[o] = conv1_b[o] * sc + bi;
    }
}

// ---------- tiled transpose+convert: src[b][rows][cols] -> dst[(b,col)][dpitch]+doff ----------
__global__ __launch_bounds__(256)
void transpose_pass(const float* __restrict__ src, unsigned short* __restrict__ dst,
                    int rows, int cols, int dpitch, int doff) {
    int b = blockIdx.z;
    int c0 = blockIdx.y * 64, p0 = blockIdx.x * 64;
    __shared__ float ts[64][65];
    int tid = threadIdx.x;
    int pl = tid & 63, r0 = tid >> 6;
    const float* sb = src + ((size_t)b * rows + c0) * cols + p0;
    if (p0 + pl < cols) {
#pragma unroll
        for (int j = 0; j < 16; ++j) {
            int cl = r0 + j * 4;
            ts[cl][pl] = sb[(size_t)cl * cols + pl];
        }
    }
    __syncthreads();
    int cl = tid & 63;
#pragma unroll
    for (int j = 0; j < 16; ++j) {
        int pl2 = r0 + j * 4;
        if (p0 + pl2 < cols)
            dst[((size_t)b * cols + p0 + pl2) * dpitch + doff + c0 + cl] = f2bf(ts[cl][pl2]);
    }
}

// ---------- MFMA GEMM: 64o x 64n, BK=32, 2-deep reg prefetch, raw-barrier pipeline ----------
// Latency-bound fix: two register stage-sets hold chunks i+1 and i+2; the ds_write of
// chunk i+1 waits (counted vmcnt, compiler-inserted) on loads issued a FULL iteration
// earlier; new loads are issued before the barrier and stay in flight across it
// (raw s_barrier + lgkmcnt(0)-only publish -- no vmcnt(0) drain per K-step).
// XCD classes balanced & bijective (m204): NT=49 -> 7,6*7; NT=98 -> 13,13,12*6, so no
// XCD idles. XCD = bx%8 (grid.x%8==0 preserves this under blockIdx.z).
// MODE 0: A=w0b, B=cov_bf bf16 strided (stride HW), N=6272(b,p); epi bn+sigmoid -> BcatT cols 0..511
// MODE 1: A=w1pT, B=BcatT contiguous rows (pitch 1536), N=6272; epi f2bf -> Pb [b][o][784]
// MODE 2: A=w1y[b], B=y f32 strided (stride QW), N=3136 (z=b); epi (acc+up(Pb))*bn relu -> out
template<int MODE, int K>
__global__ __launch_bounds__(256)
void mfma_gemm(const unsigned short* __restrict__ wpk,
               const void* __restrict__ bsrc_v,
               const unsigned short* __restrict__ Pb,
               const float* __restrict__ sA, const float* __restrict__ sB,
               void* __restrict__ outv) {
    constexpr int NIT = K / 32;                  // even for all modes
    constexpr int NT  = (MODE == 2) ? 49 : 98;   // n-tiles
    constexpr int QN = NT >> 3, REM = NT & 7;
    int bx = blockIdx.x;
    int r = bx & 7, ii = bx >> 3;
    int og = ii & 7, s = ii >> 3;
    int cnt = QN + (r < REM ? 1 : 0);
    if (s >= cnt) return;
    int t = (r < REM ? r * (QN + 1) : REM * (QN + 1) + (r - REM) * QN) + s;
    int o0 = og * 64;
    int n0 = t * 64;
    int b = blockIdx.z;
    union SM {
        struct { __align__(16) unsigned short Wt[2][2560]; __align__(16) unsigned short At[2][2560]; } s;
        float pt[(MODE == 2) ? 64 * 84 : 4];
    };
    __shared__ SM sm;
    int tid = threadIdx.x;
    int lane = tid & 63, wv = tid >> 6;
    int ln = lane & 15, quad = lane >> 4;
    int o_w = (wv >> 1) * 32, q_w = (wv & 1) * 32;
    int swr = tid >> 2, swk = (tid & 3) * 8;   // 16B staging: row, k-off
    int s_gq = tid & 63, s_gk8 = tid >> 6;     // strided staging: n, k-octet
    int qg = n0 + s_gq;
    const unsigned short* wp = (MODE == 2) ? wpk + (size_t)b * C2 * C2 : wpk;
    const unsigned short* wg = wp + (size_t)(o0 + swr) * K + swk;
    // B pointers
    const unsigned short* bg_s = nullptr;  // MODE0 strided bf16
    const unsigned short* bg_c = nullptr;  // MODE1 contiguous
    const float* bg_f = nullptr;           // MODE2 strided f32
    if (MODE == 0) {
        int bq = qg / HW, pp = qg - bq * HW;
        bg_s = (const unsigned short*)bsrc_v + ((size_t)bq * C + s_gk8 * 8) * HW + pp;
    } else if (MODE == 1) {
        bg_c = (const unsigned short*)bsrc_v + (size_t)(n0 + swr) * K + swk;
    } else {
        bg_f = (const float*)bsrc_v + ((size_t)b * C2 + s_gk8 * 8) * QW + qg;
    }

    // two register stage-sets; raw values only (pack/cvt deferred to ds_write time so
    // no VALU op forces an early vmcnt wait at load-issue time)
    uint4 stA_a, stB_a;
    uint4 stA_b, stB_b;                 // MODE1
    unsigned stA_h[8], stB_h[8];        // MODE0 (zero-extended ushort loads)
    float stA_f[8], stB_f[8];           // MODE2

#define LD_STAGE(P, CH) {                                                   \
        P##_a = *(const uint4*)(wg + (size_t)(CH) * 32);                    \
        if (MODE == 0) {                                                    \
            const unsigned short* _p = bg_s + (size_t)(CH) * 32 * HW;       \
            _Pragma("unroll")                                               \
            for (int _j = 0; _j < 8; ++_j) P##_h[_j] = _p[(size_t)_j * HW]; \
        } else if (MODE == 1) {                                             \
            P##_b = *(const uint4*)(bg_c + (size_t)(CH) * 32);              \
        } else {                                                            \
            const float* _p = bg_f + (size_t)(CH) * 32 * QW;                \
            _Pragma("unroll")                                               \
            for (int _j = 0; _j < 8; ++_j) P##_f[_j] = _p[(size_t)_j * QW]; \
        } }

#define ST_STAGE(P, BUF) {                                                  \
        *(uint4*)&sm.s.Wt[BUF][swr * 40 + swk] = P##_a;                     \
        if (MODE == 1) {                                                    \
            *(uint4*)&sm.s.At[BUF][swr * 40 + swk] = P##_b;                 \
        } else if (MODE == 0) {                                             \
            uint4 _v;                                                       \
            _v.x = P##_h[0] | (P##_h[1] << 16);                             \
            _v.y = P##_h[2] | (P##_h[3] << 16);                             \
            _v.z = P##_h[4] | (P##_h[5] << 16);                             \
            _v.w = P##_h[6] | (P##_h[7] << 16);                             \
            *(uint4*)&sm.s.At[BUF][s_gq * 40 + s_gk8 * 8] = _v;             \
        } else {                                                            \
            uint4 _v;                                                       \
            _v.x = cvt_pk_bf16(P##_f[0], P##_f[1]);                         \
            _v.y = cvt_pk_bf16(P##_f[2], P##_f[3]);                         \
            _v.z = cvt_pk_bf16(P##_f[4], P##_f[5]);                         \
            _v.w = cvt_pk_bf16(P##_f[6], P##_f[7]);                         \
            *(uint4*)&sm.s.At[BUF][s_gq * 40 + s_gk8 * 8] = _v;             \
        } }

#define GEMM_BODY(BUF, P, CHW, CHL) {                                               \
        bf16x8 af0 = *(const bf16x8*)&sm.s.Wt[BUF][(o_w + ln) * 40 + quad * 8];     \
        bf16x8 af1 = *(const bf16x8*)&sm.s.Wt[BUF][(o_w + 16 + ln) * 40 + quad * 8];\
        bf16x8 bf0 = *(const bf16x8*)&sm.s.At[BUF][(q_w + ln) * 40 + quad * 8];     \
        bf16x8 bf1 = *(const bf16x8*)&sm.s.At[BUF][(q_w + 16 + ln) * 40 + quad * 8];\
        acc[0][0] = __builtin_amdgcn_mfma_f32_16x16x32_bf16(af0, bf0, acc[0][0], 0, 0, 0); \
        acc[0][1] = __builtin_amdgcn_mfma_f32_16x16x32_bf16(af0, bf1, acc[0][1], 0, 0, 0); \
        acc[1][0] = __builtin_amdgcn_mfma_f32_16x16x32_bf16(af1, bf0, acc[1][0], 0, 0, 0); \
        acc[1][1] = __builtin_amdgcn_mfma_f32_16x16x32_bf16(af1, bf1, acc[1][1], 0, 0, 0); \
        if ((CHW) < NIT) {                                                          \
            ST_STAGE(P, (BUF) ^ 1)                                                  \
            if ((CHL) < NIT) LD_STAGE(P, (CHL))                                     \
            asm volatile("s_waitcnt lgkmcnt(0)" ::: "memory");                      \
            __builtin_amdgcn_s_barrier();                                           \
            __builtin_amdgcn_sched_barrier(0);                                      \
        } }

    // prologue: chunk0 -> LDS[0]; chunks 1,2 in flight across the barrier
    LD_STAGE(stA, 0)
    ST_STAGE(stA, 0)
    LD_STAGE(stA, 1)
    if (2 < NIT) LD_STAGE(stB, 2)
    asm volatile("s_waitcnt lgkmcnt(0)" ::: "memory");
    __builtin_amdgcn_s_barrier();
    __builtin_amdgcn_sched_barrier(0);

    f32x4 acc[2][2] = {};
    for (int i2 = 0; i2 < NIT; i2 += 2) {
        GEMM_BODY(0, stA, i2 + 1, i2 + 3)
        GEMM_BODY(1, stB, i2 + 2, i2 + 4)
    }
#undef GEMM_BODY
#undef ST_STAGE
#undef LD_STAGE

    // ---- epilogue; D: row = quad*4+reg, col = ln ----
    if (MODE == 2) {
        float* outp = (float*)outv;
        __syncthreads();
        int h0 = n0 / 56;
        int hmin = (h0 & 1) ? (h0 >> 1) : max(0, (h0 >> 1) - 1);
        for (int e = tid; e < 64 * 84; e += 256) {
            int o_l = e / 84, rem = e - o_l * 84;
            int s2 = rem / 28, w = rem - s2 * 28;
            int row = min(hmin + s2, 27);
            sm.pt[e] = ld_f(&Pb[((size_t)b * C2 + o0 + o_l) * HW + row * 28 + w]);
        }
        __syncthreads();
#pragma unroll
        for (int nt = 0; nt < 2; ++nt) {
            int q = n0 + q_w + nt * 16 + ln;
            int hq = q / 56, wq = q - hq * 56;
            int hm = hq >> 1, wm = wq >> 1;
            int hn = (hq & 1) ? min(hm + 1, 27) : max(hm - 1, 0);
            int wn_ = (wq & 1) ? min(wm + 1, 27) : max(wm - 1, 0);
            int rm_ = (hm - hmin) * 28, rn_ = (hn - hmin) * 28;
#pragma unroll
            for (int mt = 0; mt < 2; ++mt)
#pragma unroll
                for (int reg = 0; reg < 4; ++reg) {
                    int ol = o_w + mt * 16 + quad * 4 + reg;
                    int o = o0 + ol;
                    const float* Pt = &sm.pt[ol * 84];
                    float up = 0.5625f * Pt[rm_ + wm] + 0.1875f * (Pt[rm_ + wn_] + Pt[rn_ + wm])
                             + 0.0625f * Pt[rn_ + wn_];
                    float v = (acc[mt][nt][reg] + up) * sA[o] + sB[o];
                    outp[((size_t)b * C2 + o) * QW + q] = fmaxf(v, 0.f);
                }
        }
    } else if (MODE == 0) {
        unsigned short* outp = (unsigned short*)outv;   // BcatT, pitch 1536, cols 0..511
#pragma unroll
        for (int nt = 0; nt < 2; ++nt) {
            int n = n0 + q_w + nt * 16 + ln;
#pragma unroll
            for (int mt = 0; mt < 2; ++mt) {
                int ob = o0 + o_w + mt * 16 + quad * 4;
                unsigned short pk[4];
#pragma unroll
                for (int reg = 0; reg < 4; ++reg) {
                    int o = ob + reg;
                    float v = acc[mt][nt][reg] * sA[o] + sB[o];
                    pk[reg] = f2bf(1.f / (1.f + expf(-v)));
                }
                *(uint2*)&outp[(size_t)n * 1536 + ob] = *(uint2*)pk;
            }
        }
    } else {
        unsigned short* outp = (unsigned short*)outv;   // Pb [b][o][784] bf16
#pragma unroll
        for (int nt = 0; nt < 2; ++nt) {
            int n = n0 + q_w + nt * 16 + ln;
            int be = n / HW, pe = n - be * HW;
#pragma unroll
            for (int mt = 0; mt < 2; ++mt)
#pragma unroll
                for (int reg = 0; reg < 4; ++reg) {
                    int o = o0 + o_w + mt * 16 + quad * 4 + reg;
                    outp[((size_t)be * C2 + o) * HW + pe] = f2bf(acc[mt][nt][reg]);
                }
        }
    }
}

extern "C" void kernel_launch(void* const* d_in, const int* in_sizes, int n_in,
                              void* d_out, int out_size, void* d_ws, size_t ws_size,
                              hipStream_t stream) {
    const float* y       = (const float*)d_in[0];
    const float* x       = (const float*)d_in[1];
    const float* fc1_w   = (const float*)d_in[2];
    const float* fc2_w   = (const float*)d_in[3];
    const float* conv_w  = (const float*)d_in[4];
    const float* conv_b  = (const float*)d_in[5];
    const float* conv1_w = (const float*)d_in[6];
    const float* conv1_b = (const float*)d_in[7];
    const float* bn_g    = (const float*)d_in[8];
    const float* bn_b    = (const float*)d_in[9];
    const float* bn_m    = (const float*)d_in[10];
    const float* bn_v    = (const float*)d_in[11];
    const float* dw_w    = (const float*)d_in[12];
    const float* dw_b    = (const float*)d_in[13];
    float* out = (float*)d_out;

    // ---- workspace carve: NO aliasing; total = 45,389,824 B (== Round-2-proven extent) ----
    float* ws  = (float*)d_ws;
    float* s0  = ws;                 // 4096
    float* att = ws + 4096;          // 4096
    float* sA  = ws + 8192;          // 512
    float* sB0 = ws + 8704;          // 512
    float* sB1 = ws + 9216;          // 512 -> header ends at float 9728 (byte 38912, 16B-aligned)
    unsigned short* w0b    = (unsigned short*)(ws + 9728);   // 512*1024 sh
    unsigned short* w1y    = w0b + (size_t)C2 * C;           // 8*512*512 sh
    unsigned short* w1pT   = w1y + (size_t)B * C2 * C2;      // 512*1536 sh
    unsigned short* cov_bf = w1pT + (size_t)C2 * 1536;       // 8*1024*784 sh
    unsigned short* BcatT  = cov_bf + (size_t)B * C * HW;    // 6272*1536 sh
    unsigned short* Pb     = BcatT + (size_t)B * HW * 1536;  // 8*512*784 sh

    gap_kernel<<<B * C2, 256, 0, stream>>>(y, s0);
    se_fc_kernel<<<B, 256, 0, stream>>>(s0, fc1_w, fc2_w, att);
    pack_w<<<C2, 256, 0, stream>>>(conv_w, conv_b, conv1_w, conv1_b,
                                   bn_g, bn_b, bn_m, bn_v, att,
                                   w0b, w1y, w1pT, sA, sB0, sB1);
    dwcov_kernel<<<B * C, 256, 0, stream>>>(x, dw_w, dw_b, cov_bf);
    // xT: x[b][c][p] -> BcatT[(b,p)][512+c]
    transpose_pass<<<dim3(13, 16, B), 256, 0, stream>>>(x, BcatT, C, HW, 1536, 512);
    // M0: x2s = sigmoid(bn(conv(cov))) -> BcatT cols 0..511  (98 tiles: classes 13,13,12x6 -> grid 8*8*13)
    mfma_gemm<0, 1024><<<dim3(832), 256, 0, stream>>>(w0b, cov_bf, nullptr, sA, sB0, BcatT);
    // M1: Pb = w1[:,512:]·[x2s|x]  (bf16)
    mfma_gemm<1, 1536><<<dim3(832), 256, 0, stream>>>(w1pT, BcatT, nullptr, sA, sB0, Pb);
    // M2: out = relu(bn(w1y[b]·y + up(Pb)))  (49 tiles: classes 7,6x7 -> grid 8*8*7 per batch)
    mfma_gemm<2, 512><<<dim3(448, 1, B), 256, 0, stream>>>(w1y, y, Pb, sA, sB1, out);
}